// Round 8
// baseline (793.969 us; speedup 1.0000x reference)
//
#include <hip/hip_runtime.h>

// ---------------------------------------------------------------------------
// BikeSafetyGNN: 3-layer GraphSAGE (mean) + 2 linear heads, fp32.
// R8: (a) T packed to 4 B/edge ((dloc<<18)|src) -> halves k_bucket write and
//         k_csr read traffic; bcur zeroing folded into k_bscan.
//     (b) gather at 16 B/lane (uint4 = 8 bf16 ch): half the VMEM insts,
//         2x in-flight bytes/lane. Probe: latency-limited vs L2-miss-BW-bound.
// ---------------------------------------------------------------------------

typedef __bf16 bf16x8 __attribute__((ext_vector_type(8)));
typedef float  f32x4  __attribute__((ext_vector_type(4)));

__device__ __forceinline__ unsigned short f2bf_rne(float f) {
    unsigned int u = __float_as_uint(f);
    u = (u + 0x7FFFu + ((u >> 16) & 1u)) >> 16;
    return (unsigned short)u;
}

// unpack 8 bf16 (uint4) and accumulate into two float4s
__device__ __forceinline__ void bfacc8(float4& lo, float4& hi, const uint4 q) {
    lo.x += __uint_as_float(q.x << 16);
    lo.y += __uint_as_float(q.x & 0xFFFF0000u);
    lo.z += __uint_as_float(q.y << 16);
    lo.w += __uint_as_float(q.y & 0xFFFF0000u);
    hi.x += __uint_as_float(q.z << 16);
    hi.y += __uint_as_float(q.z & 0xFFFF0000u);
    hi.z += __uint_as_float(q.w << 16);
    hi.w += __uint_as_float(q.w & 0xFFFF0000u);
}

// ---------------- CSR build (bucket = dst >> 10) ----------------

__global__ __launch_bounds__(256) void k_bcount(const int* __restrict__ dst, int E, int N,
                                                int* __restrict__ bcnt) {
    __shared__ int h[256];
    const int tid = threadIdx.x;
    h[tid] = 0;
    __syncthreads();
    const int stride = gridDim.x * 256;
    for (int i = blockIdx.x * 256 + tid; i < E; i += stride) {
        int d = dst[i];
        d = d < 0 ? 0 : (d >= N ? N - 1 : d);
        atomicAdd(&h[d >> 10], 1);
    }
    __syncthreads();
    if (h[tid]) atomicAdd(&bcnt[tid], h[tid]);
}

__global__ __launch_bounds__(256) void k_bscan(const int* __restrict__ bcnt,
                                               int* __restrict__ boff,
                                               int* __restrict__ bcur, int NBK, int E) {
    __shared__ int sd[256];
    const int tid = threadIdx.x;
    bcur[tid] = 0;                            // folded memset
    int v = (tid < NBK) ? bcnt[tid] : 0;
    sd[tid] = v; __syncthreads();
    for (int off = 1; off < 256; off <<= 1) {
        int t = (tid >= off) ? sd[tid - off] : 0;
        __syncthreads();
        sd[tid] += t;
        __syncthreads();
    }
    if (tid < NBK) boff[tid] = sd[tid] - v;   // exclusive
    if (tid == 0) boff[NBK] = E;
}

// tile-local LDS counting sort; T entry = (dloc<<18) | src  (4 B/edge)
#define BTILE 4096
__global__ __launch_bounds__(256) void k_bucket(const int* __restrict__ src,
                                                const int* __restrict__ dst, int E, int N,
                                                const int* __restrict__ boff,
                                                int* __restrict__ bcur,
                                                int* __restrict__ T, int NBK) {
    __shared__ int cnt[256], cnt2[256], lofs[256], gbase[256], boffs[256], sd[256];
    __shared__ int2 staged[BTILE];
    const int tid = threadIdx.x;
    const int tb = blockIdx.x * BTILE;
    const int tn = min(BTILE, E - tb);
    cnt[tid] = 0; cnt2[tid] = 0;
    boffs[tid] = (tid < NBK) ? boff[tid] : 0;
    __syncthreads();
    for (int i = tid; i < tn; i += 256) {
        int d = dst[tb + i];
        d = d < 0 ? 0 : (d >= N ? N - 1 : d);
        atomicAdd(&cnt[d >> 10], 1);
    }
    __syncthreads();
    int v = cnt[tid];
    sd[tid] = v; __syncthreads();
    for (int off = 1; off < 256; off <<= 1) {
        int t = (tid >= off) ? sd[tid - off] : 0;
        __syncthreads();
        sd[tid] += t;
        __syncthreads();
    }
    lofs[tid] = sd[tid] - v;
    if (v > 0 && tid < NBK) gbase[tid] = atomicAdd(&bcur[tid], v);
    __syncthreads();
    for (int i = tid; i < tn; i += 256) {
        int d = dst[tb + i];
        d = d < 0 ? 0 : (d >= N ? N - 1 : d);
        int s = src[tb + i];
        s = s < 0 ? 0 : (s >= N ? N - 1 : s);
        int b = d >> 10;
        int r = atomicAdd(&cnt2[b], 1);
        staged[lofs[b] + r] = make_int2(s, d);
    }
    __syncthreads();
    for (int i = tid; i < tn; i += 256) {
        int2 p = staged[i];
        int b = p.y >> 10;
        T[(size_t)boffs[b] + gbase[b] + (i - lofs[b])] = ((p.y & 1023) << 18) | p.x;
    }
}

// per bucket: LDS degree histogram + 1024-wide scan -> rowptr, then LDS-cursor
// fill of adj (packed T: dloc = p>>18, src = p & 0x3FFFF)
__global__ __launch_bounds__(1024) void k_csr(const int* __restrict__ T,
                                              const int* __restrict__ boff,
                                              int* __restrict__ rowptr,
                                              int* __restrict__ adj, int N, int E) {
    __shared__ int hist[1024];
    __shared__ int sc[1024];
    const int tid = threadIdx.x;
    const int b = blockIdx.x;
    const int node0 = b << 10;
    hist[tid] = 0;
    __syncthreads();
    const int beg = boff[b], end = boff[b + 1];
    for (int i = beg + tid; i < end; i += 1024)
        atomicAdd(&hist[((unsigned)T[i]) >> 18], 1);
    __syncthreads();
    int v = hist[tid];
    sc[tid] = v;
    __syncthreads();
    for (int off = 1; off < 1024; off <<= 1) {
        int t = (tid >= off) ? sc[tid - off] : 0;
        __syncthreads();
        sc[tid] += t;
        __syncthreads();
    }
    const int excl = beg + sc[tid] - v;
    const int n = node0 + tid;
    if (n < N) rowptr[n] = excl;
    if (b == 0 && tid == 0) rowptr[N] = E;
    hist[tid] = excl;
    __syncthreads();
    for (int i = beg + tid; i < end; i += 1024) {
        unsigned p = (unsigned)T[i];
        int pos = atomicAdd(&hist[p >> 18], 1);
        adj[pos] = (int)(p & 0x3FFFFu);
    }
}

// ---------------- MFMA fused projection ----------------
template<int DIN, int DOUT>
__global__ __launch_bounds__(256) void proj_mfma(const float* __restrict__ H,
                                                 const float* __restrict__ Wl,
                                                 const float* __restrict__ Wr,
                                                 const float* __restrict__ bias,
                                                 unsigned short* __restrict__ Pl,
                                                 float* __restrict__ R, int N) {
    constexpr int SP = DIN + 8;
    constexpr int COLT = DOUT / 16;
    __shared__ __bf16 lwl[DOUT * SP];
    __shared__ __bf16 lwrh[DOUT * SP];
    __shared__ __bf16 lwrl[DOUT * SP];
    for (int idx = threadIdx.x; idx < DIN * DOUT; idx += 256) {
        int c = idx / DIN, k = idx % DIN;
        float wl = Wl[idx], wr = Wr[idx];
        __bf16 wrh = (__bf16)wr;
        lwl[c * SP + k] = (__bf16)wl;
        lwrh[c * SP + k] = wrh;
        lwrl[c * SP + k] = (__bf16)(wr - (float)wrh);
    }
    __syncthreads();
    const int wave = threadIdx.x >> 6, lane = threadIdx.x & 63;
    const int quad = lane >> 4, l16 = lane & 15;
    const int n0 = (blockIdx.x * 4 + wave) * 16;
    int arow = n0 + l16;
    if (arow >= N) arow = N - 1;
    const float* hrow = H + (size_t)arow * DIN;

    f32x4 zero = {0.f, 0.f, 0.f, 0.f};
    f32x4 accP[COLT], accR[COLT];
    #pragma unroll
    for (int t = 0; t < COLT; ++t) { accP[t] = zero; accR[t] = zero; }

    for (int k0 = 0; k0 < DIN; k0 += 32) {
        const float* hp = hrow + k0 + quad * 8;
        float4 h0 = *(const float4*)hp;
        float4 h1 = *(const float4*)(hp + 4);
        float hv[8] = {h0.x, h0.y, h0.z, h0.w, h1.x, h1.y, h1.z, h1.w};
        bf16x8 ahi, alo;
        #pragma unroll
        for (int j = 0; j < 8; ++j) {
            __bf16 hb = (__bf16)hv[j];
            ahi[j] = hb;
            alo[j] = (__bf16)(hv[j] - (float)hb);
        }
        const int kk = k0 + quad * 8;
        #pragma unroll
        for (int t = 0; t < COLT; ++t) {
            const int c = t * 16 + l16;
            bf16x8 bl  = *(const bf16x8*)&lwl [c * SP + kk];
            bf16x8 brh = *(const bf16x8*)&lwrh[c * SP + kk];
            bf16x8 brl = *(const bf16x8*)&lwrl[c * SP + kk];
            accP[t] = __builtin_amdgcn_mfma_f32_16x16x32_bf16(ahi, bl,  accP[t], 0, 0, 0);
            accR[t] = __builtin_amdgcn_mfma_f32_16x16x32_bf16(ahi, brh, accR[t], 0, 0, 0);
            accR[t] = __builtin_amdgcn_mfma_f32_16x16x32_bf16(ahi, brl, accR[t], 0, 0, 0);
            accR[t] = __builtin_amdgcn_mfma_f32_16x16x32_bf16(alo, brh, accR[t], 0, 0, 0);
        }
    }
    #pragma unroll
    for (int t = 0; t < COLT; ++t) {
        const int c = t * 16 + l16;
        const float bc = bias[c];
        #pragma unroll
        for (int r = 0; r < 4; ++r) {
            int node = n0 + quad * 4 + r;
            if (node < N) {
                Pl[(size_t)node * DOUT + c] = f2bf_rne(accP[t][r]);
                R[(size_t)node * DOUT + c] = accR[t][r] + bc;
            }
        }
    }
}

// ---------------- gather: Hout = relu( mean P[j] + Hout ), P bf16, 16 B/lane ----

template<int DOUT> struct GatherCfg {
    static constexpr int L   = DOUT / 8;   // uint4s (8 bf16) per node row
    static constexpr int S   = 64 / L;     // nodes concurrently per wave
    static constexpr int M   = 4;          // sequential nodes per subgroup
    static constexpr int NPW = S * M;
    static constexpr int NPB = NPW * 4;    // 4 waves/block
};

template<int DOUT>
__global__ __launch_bounds__(256, 6) void gather_kernel(const unsigned short* __restrict__ P,
                                                        const int* __restrict__ rowptr,
                                                        const int* __restrict__ adj,
                                                        float* __restrict__ Hout, int N) {
    using C = GatherCfg<DOUT>;
    constexpr int L = C::L, S = C::S, M = C::M;
    constexpr int NPW = C::NPW, NPB = C::NPB;
    const int wave = threadIdx.x >> 6, lane = threadIdx.x & 63;
    const int sub = lane / L, cl = lane % L;
    const uint4* __restrict__ P4 = (const uint4*)P;
    float4* __restrict__ H4 = (float4*)Hout;
    const int base = blockIdx.x * NPB + wave * NPW + sub;
    #pragma unroll 1
    for (int m = 0; m < M; ++m) {
        int n = base + m * S;
        if (n >= N) continue;
        int beg = rowptr[n], end = rowptr[n + 1];
        float4 a0l = {0,0,0,0}, a0h = {0,0,0,0}, a1l = {0,0,0,0}, a1h = {0,0,0,0};
        int j = beg;
        while (j < end && (j & 3)) { bfacc8(a0l, a0h, P4[(size_t)adj[j] * L + cl]); ++j; }
        for (; j + 8 <= end; j += 8) {
            int4 sA = *(const int4*)(adj + j);
            int4 sB = *(const int4*)(adj + j + 4);
            uint4 q0 = P4[(size_t)sA.x * L + cl];
            uint4 q1 = P4[(size_t)sA.y * L + cl];
            uint4 q2 = P4[(size_t)sA.z * L + cl];
            uint4 q3 = P4[(size_t)sA.w * L + cl];
            uint4 q4 = P4[(size_t)sB.x * L + cl];
            uint4 q5 = P4[(size_t)sB.y * L + cl];
            uint4 q6 = P4[(size_t)sB.z * L + cl];
            uint4 q7 = P4[(size_t)sB.w * L + cl];
            bfacc8(a0l, a0h, q0); bfacc8(a1l, a1h, q1);
            bfacc8(a0l, a0h, q2); bfacc8(a1l, a1h, q3);
            bfacc8(a0l, a0h, q4); bfacc8(a1l, a1h, q5);
            bfacc8(a0l, a0h, q6); bfacc8(a1l, a1h, q7);
        }
        if (j + 4 <= end) {
            int4 sA = *(const int4*)(adj + j);
            bfacc8(a0l, a0h, P4[(size_t)sA.x * L + cl]);
            bfacc8(a1l, a1h, P4[(size_t)sA.y * L + cl]);
            bfacc8(a0l, a0h, P4[(size_t)sA.z * L + cl]);
            bfacc8(a1l, a1h, P4[(size_t)sA.w * L + cl]);
            j += 4;
        }
        for (; j < end; ++j) bfacc8(a0l, a0h, P4[(size_t)adj[j] * L + cl]);
        int deg = end - beg;
        float inv = deg > 0 ? 1.0f / (float)deg : 0.0f;
        float4 rlo = H4[(size_t)n * L * 2 + cl * 2];
        float4 rhi = H4[(size_t)n * L * 2 + cl * 2 + 1];
        float4 olo, ohi;
        olo.x = fmaxf((a0l.x + a1l.x) * inv + rlo.x, 0.0f);
        olo.y = fmaxf((a0l.y + a1l.y) * inv + rlo.y, 0.0f);
        olo.z = fmaxf((a0l.z + a1l.z) * inv + rlo.z, 0.0f);
        olo.w = fmaxf((a0l.w + a1l.w) * inv + rlo.w, 0.0f);
        ohi.x = fmaxf((a0h.x + a1h.x) * inv + rhi.x, 0.0f);
        ohi.y = fmaxf((a0h.y + a1h.y) * inv + rhi.y, 0.0f);
        ohi.z = fmaxf((a0h.z + a1h.z) * inv + rhi.z, 0.0f);
        ohi.w = fmaxf((a0h.w + a1h.w) * inv + rhi.w, 0.0f);
        H4[(size_t)n * L * 2 + cl * 2]     = olo;
        H4[(size_t)n * L * 2 + cl * 2 + 1] = ohi;
    }
}

__global__ __launch_bounds__(256) void k_head(const float* __restrict__ H3,
                                              const float* __restrict__ Wreg,
                                              const float* __restrict__ breg,
                                              const float* __restrict__ Wcls,
                                              const float* __restrict__ bcls,
                                              float* __restrict__ out, int N) {
    int i = blockIdx.x * 256 + threadIdx.x;
    if (i >= N) return;
    const float4* h = (const float4*)(H3 + (size_t)i * 16);
    float reg = 0.f, cls = 0.f;
    #pragma unroll
    for (int k4 = 0; k4 < 4; ++k4) {
        float4 hv = h[k4];
        float4 wr = ((const float4*)Wreg)[k4];
        float4 wc = ((const float4*)Wcls)[k4];
        reg += hv.x * wr.x + hv.y * wr.y + hv.z * wr.z + hv.w * wr.w;
        cls += hv.x * wc.x + hv.y * wc.y + hv.z * wc.z + hv.w * wc.w;
    }
    out[i] = reg + breg[0];
    out[(size_t)N + i] = cls + bcls[0];
}

extern "C" void kernel_launch(void* const* d_in, const int* in_sizes, int n_in,
                              void* d_out, int out_size, void* d_ws, size_t ws_size,
                              hipStream_t stream) {
    const float* x    = (const float*)d_in[0];
    const int*   ei   = (const int*)d_in[1];
    const float* W1l  = (const float*)d_in[2];
    const float* b1l  = (const float*)d_in[3];
    const float* W1r  = (const float*)d_in[4];
    const float* W2l  = (const float*)d_in[5];
    const float* b2l  = (const float*)d_in[6];
    const float* W2r  = (const float*)d_in[7];
    const float* W3l  = (const float*)d_in[8];
    const float* b3l  = (const float*)d_in[9];
    const float* W3r  = (const float*)d_in[10];
    const float* Wreg = (const float*)d_in[11];
    const float* breg = (const float*)d_in[12];
    const float* Wcls = (const float*)d_in[13];
    const float* bcls = (const float*)d_in[14];

    const int N = in_sizes[0] / 128;
    const int E = in_sizes[1] / 2;
    const int* src = ei;
    const int* dst = ei + E;

    char* ws = (char*)d_ws;
    size_t off = 0;
    auto alloc = [&](size_t bytes) -> void* {
        void* p = ws + off;
        off += (bytes + 255) & ~(size_t)255;
        return p;
    };
    int*   rowptr = (int*)alloc((size_t)(N + 1) * 4);
    int*   bcnt   = (int*)alloc(1024);
    int*   bcur   = (int*)alloc(1024);
    int*   boff   = (int*)alloc(1028);
    int*   adj    = (int*)alloc((size_t)E * 4);
    unsigned short* A = (unsigned short*)alloc((size_t)N * 64 * 2);  // bf16 P
    float* B      = (float*)alloc((size_t)N * 64 * 4);  // h1; doubles as T during CSR build
    float* C      = (float*)alloc((size_t)N * 32 * 4);  // h2
    float* D      = (float*)alloc((size_t)N * 16 * 4);  // h3
    int*   T      = (int*)B;                             // packed edges, E*4B <= N*64*4B

    const int NBK = (N + 1023) >> 10;     // buckets (196; must be <= 256)

    // ---- CSR build ----
    hipMemsetAsync(bcnt, 0, 1024, stream);
    k_bcount<<<1024, 256, 0, stream>>>(dst, E, N, bcnt);
    k_bscan<<<1, 256, 0, stream>>>(bcnt, boff, bcur, NBK, E);
    k_bucket<<<(E + BTILE - 1) / BTILE, 256, 0, stream>>>(src, dst, E, N, boff, bcur, T, NBK);
    k_csr<<<NBK, 1024, 0, stream>>>(T, boff, rowptr, adj, N, E);

    const int PB = 64;   // nodes per proj_mfma block (4 waves x 16)
    constexpr int G64 = GatherCfg<64>::NPB;
    constexpr int G32 = GatherCfg<32>::NPB;
    constexpr int G16 = GatherCfg<16>::NPB;

    // ---- layer 1: 128 -> 64 ----
    proj_mfma<128, 64><<<(N + PB - 1) / PB, 256, 0, stream>>>(x, W1l, W1r, b1l, A, B, N);
    gather_kernel<64><<<(N + G64 - 1) / G64, 256, 0, stream>>>(A, rowptr, adj, B, N);
    // ---- layer 2: 64 -> 32 ----
    proj_mfma<64, 32><<<(N + PB - 1) / PB, 256, 0, stream>>>(B, W2l, W2r, b2l, A, C, N);
    gather_kernel<32><<<(N + G32 - 1) / G32, 256, 0, stream>>>(A, rowptr, adj, C, N);
    // ---- layer 3: 32 -> 16 ----
    proj_mfma<32, 16><<<(N + PB - 1) / PB, 256, 0, stream>>>(C, W3l, W3r, b3l, A, D, N);
    gather_kernel<16><<<(N + G16 - 1) / G16, 256, 0, stream>>>(A, rowptr, adj, D, N);

    // ---- heads ----
    k_head<<<(N + 255) / 256, 256, 0, stream>>>(D, Wreg, breg, Wcls, bcls, (float*)d_out, N);
}

// Round 9
// 730.812 us; speedup vs baseline: 1.0864x; 1.0864x over previous
//
#include <hip/hip_runtime.h>

// ---------------------------------------------------------------------------
// BikeSafetyGNN: 3-layer GraphSAGE (mean) + 2 linear heads, fp32.
// R9: revert gather to R7 uint2 shape (16 lanes x 8 B = full 128 B row/node,
//     full-line Hout writes — R8's 16 B/lane caused RFO write amplification).
//     Keep R8a: T packed to 4 B/edge, bcur zeroing folded into k_bscan.
// ---------------------------------------------------------------------------

typedef __bf16 bf16x8 __attribute__((ext_vector_type(8)));
typedef float  f32x4  __attribute__((ext_vector_type(4)));

__device__ __forceinline__ unsigned short f2bf_rne(float f) {
    unsigned int u = __float_as_uint(f);
    u = (u + 0x7FFFu + ((u >> 16) & 1u)) >> 16;
    return (unsigned short)u;
}

// unpack 4 bf16 (packed little-endian in uint2) and accumulate into float4
__device__ __forceinline__ void bfacc(float4& a, const uint2 q) {
    a.x += __uint_as_float(q.x << 16);
    a.y += __uint_as_float(q.x & 0xFFFF0000u);
    a.z += __uint_as_float(q.y << 16);
    a.w += __uint_as_float(q.y & 0xFFFF0000u);
}

// ---------------- CSR build (bucket = dst >> 10) ----------------

__global__ __launch_bounds__(256) void k_bcount(const int* __restrict__ dst, int E, int N,
                                                int* __restrict__ bcnt) {
    __shared__ int h[256];
    const int tid = threadIdx.x;
    h[tid] = 0;
    __syncthreads();
    const int stride = gridDim.x * 256;
    for (int i = blockIdx.x * 256 + tid; i < E; i += stride) {
        int d = dst[i];
        d = d < 0 ? 0 : (d >= N ? N - 1 : d);
        atomicAdd(&h[d >> 10], 1);
    }
    __syncthreads();
    if (h[tid]) atomicAdd(&bcnt[tid], h[tid]);
}

__global__ __launch_bounds__(256) void k_bscan(const int* __restrict__ bcnt,
                                               int* __restrict__ boff,
                                               int* __restrict__ bcur, int NBK, int E) {
    __shared__ int sd[256];
    const int tid = threadIdx.x;
    bcur[tid] = 0;                            // folded memset
    int v = (tid < NBK) ? bcnt[tid] : 0;
    sd[tid] = v; __syncthreads();
    for (int off = 1; off < 256; off <<= 1) {
        int t = (tid >= off) ? sd[tid - off] : 0;
        __syncthreads();
        sd[tid] += t;
        __syncthreads();
    }
    if (tid < NBK) boff[tid] = sd[tid] - v;   // exclusive
    if (tid == 0) boff[NBK] = E;
}

// tile-local LDS counting sort; T entry = (dloc<<18) | src  (4 B/edge)
#define BTILE 4096
__global__ __launch_bounds__(256) void k_bucket(const int* __restrict__ src,
                                                const int* __restrict__ dst, int E, int N,
                                                const int* __restrict__ boff,
                                                int* __restrict__ bcur,
                                                int* __restrict__ T, int NBK) {
    __shared__ int cnt[256], cnt2[256], lofs[256], gbase[256], boffs[256], sd[256];
    __shared__ int2 staged[BTILE];
    const int tid = threadIdx.x;
    const int tb = blockIdx.x * BTILE;
    const int tn = min(BTILE, E - tb);
    cnt[tid] = 0; cnt2[tid] = 0;
    boffs[tid] = (tid < NBK) ? boff[tid] : 0;
    __syncthreads();
    for (int i = tid; i < tn; i += 256) {
        int d = dst[tb + i];
        d = d < 0 ? 0 : (d >= N ? N - 1 : d);
        atomicAdd(&cnt[d >> 10], 1);
    }
    __syncthreads();
    int v = cnt[tid];
    sd[tid] = v; __syncthreads();
    for (int off = 1; off < 256; off <<= 1) {
        int t = (tid >= off) ? sd[tid - off] : 0;
        __syncthreads();
        sd[tid] += t;
        __syncthreads();
    }
    lofs[tid] = sd[tid] - v;
    if (v > 0 && tid < NBK) gbase[tid] = atomicAdd(&bcur[tid], v);
    __syncthreads();
    for (int i = tid; i < tn; i += 256) {
        int d = dst[tb + i];
        d = d < 0 ? 0 : (d >= N ? N - 1 : d);
        int s = src[tb + i];
        s = s < 0 ? 0 : (s >= N ? N - 1 : s);
        int b = d >> 10;
        int r = atomicAdd(&cnt2[b], 1);
        staged[lofs[b] + r] = make_int2(s, d);
    }
    __syncthreads();
    for (int i = tid; i < tn; i += 256) {
        int2 p = staged[i];
        int b = p.y >> 10;
        T[(size_t)boffs[b] + gbase[b] + (i - lofs[b])] = ((p.y & 1023) << 18) | p.x;
    }
}

// per bucket: LDS degree histogram + 1024-wide scan -> rowptr, then LDS-cursor
// fill of adj (packed T: dloc = p>>18, src = p & 0x3FFFF)
__global__ __launch_bounds__(1024) void k_csr(const int* __restrict__ T,
                                              const int* __restrict__ boff,
                                              int* __restrict__ rowptr,
                                              int* __restrict__ adj, int N, int E) {
    __shared__ int hist[1024];
    __shared__ int sc[1024];
    const int tid = threadIdx.x;
    const int b = blockIdx.x;
    const int node0 = b << 10;
    hist[tid] = 0;
    __syncthreads();
    const int beg = boff[b], end = boff[b + 1];
    for (int i = beg + tid; i < end; i += 1024)
        atomicAdd(&hist[((unsigned)T[i]) >> 18], 1);
    __syncthreads();
    int v = hist[tid];
    sc[tid] = v;
    __syncthreads();
    for (int off = 1; off < 1024; off <<= 1) {
        int t = (tid >= off) ? sc[tid - off] : 0;
        __syncthreads();
        sc[tid] += t;
        __syncthreads();
    }
    const int excl = beg + sc[tid] - v;
    const int n = node0 + tid;
    if (n < N) rowptr[n] = excl;
    if (b == 0 && tid == 0) rowptr[N] = E;
    hist[tid] = excl;
    __syncthreads();
    for (int i = beg + tid; i < end; i += 1024) {
        unsigned p = (unsigned)T[i];
        int pos = atomicAdd(&hist[p >> 18], 1);
        adj[pos] = (int)(p & 0x3FFFFu);
    }
}

// ---------------- MFMA fused projection ----------------
template<int DIN, int DOUT>
__global__ __launch_bounds__(256) void proj_mfma(const float* __restrict__ H,
                                                 const float* __restrict__ Wl,
                                                 const float* __restrict__ Wr,
                                                 const float* __restrict__ bias,
                                                 unsigned short* __restrict__ Pl,
                                                 float* __restrict__ R, int N) {
    constexpr int SP = DIN + 8;
    constexpr int COLT = DOUT / 16;
    __shared__ __bf16 lwl[DOUT * SP];
    __shared__ __bf16 lwrh[DOUT * SP];
    __shared__ __bf16 lwrl[DOUT * SP];
    for (int idx = threadIdx.x; idx < DIN * DOUT; idx += 256) {
        int c = idx / DIN, k = idx % DIN;
        float wl = Wl[idx], wr = Wr[idx];
        __bf16 wrh = (__bf16)wr;
        lwl[c * SP + k] = (__bf16)wl;
        lwrh[c * SP + k] = wrh;
        lwrl[c * SP + k] = (__bf16)(wr - (float)wrh);
    }
    __syncthreads();
    const int wave = threadIdx.x >> 6, lane = threadIdx.x & 63;
    const int quad = lane >> 4, l16 = lane & 15;
    const int n0 = (blockIdx.x * 4 + wave) * 16;
    int arow = n0 + l16;
    if (arow >= N) arow = N - 1;
    const float* hrow = H + (size_t)arow * DIN;

    f32x4 zero = {0.f, 0.f, 0.f, 0.f};
    f32x4 accP[COLT], accR[COLT];
    #pragma unroll
    for (int t = 0; t < COLT; ++t) { accP[t] = zero; accR[t] = zero; }

    for (int k0 = 0; k0 < DIN; k0 += 32) {
        const float* hp = hrow + k0 + quad * 8;
        float4 h0 = *(const float4*)hp;
        float4 h1 = *(const float4*)(hp + 4);
        float hv[8] = {h0.x, h0.y, h0.z, h0.w, h1.x, h1.y, h1.z, h1.w};
        bf16x8 ahi, alo;
        #pragma unroll
        for (int j = 0; j < 8; ++j) {
            __bf16 hb = (__bf16)hv[j];
            ahi[j] = hb;
            alo[j] = (__bf16)(hv[j] - (float)hb);
        }
        const int kk = k0 + quad * 8;
        #pragma unroll
        for (int t = 0; t < COLT; ++t) {
            const int c = t * 16 + l16;
            bf16x8 bl  = *(const bf16x8*)&lwl [c * SP + kk];
            bf16x8 brh = *(const bf16x8*)&lwrh[c * SP + kk];
            bf16x8 brl = *(const bf16x8*)&lwrl[c * SP + kk];
            accP[t] = __builtin_amdgcn_mfma_f32_16x16x32_bf16(ahi, bl,  accP[t], 0, 0, 0);
            accR[t] = __builtin_amdgcn_mfma_f32_16x16x32_bf16(ahi, brh, accR[t], 0, 0, 0);
            accR[t] = __builtin_amdgcn_mfma_f32_16x16x32_bf16(ahi, brl, accR[t], 0, 0, 0);
            accR[t] = __builtin_amdgcn_mfma_f32_16x16x32_bf16(alo, brh, accR[t], 0, 0, 0);
        }
    }
    // C/D layout: col = lane&15, row = quad*4 + reg  [m89-verified]
    #pragma unroll
    for (int t = 0; t < COLT; ++t) {
        const int c = t * 16 + l16;
        const float bc = bias[c];
        #pragma unroll
        for (int r = 0; r < 4; ++r) {
            int node = n0 + quad * 4 + r;
            if (node < N) {
                Pl[(size_t)node * DOUT + c] = f2bf_rne(accP[t][r]);
                R[(size_t)node * DOUT + c] = accR[t][r] + bc;
            }
        }
    }
}

// ---------------- gather: Hout = relu( mean P[j] + Hout ), P bf16, 8 B/lane ----

template<int DOUT> struct GatherCfg {
    static constexpr int L   = DOUT / 4;   // uint2s (4 bf16) per node row
    static constexpr int S   = 64 / L;     // nodes concurrently per wave
    static constexpr int M   = 4;          // sequential nodes per subgroup
    static constexpr int NPW = S * M;
    static constexpr int NPB = NPW * 4;    // 4 waves/block
};

template<int DOUT>
__global__ __launch_bounds__(256, 6) void gather_kernel(const unsigned short* __restrict__ P,
                                                        const int* __restrict__ rowptr,
                                                        const int* __restrict__ adj,
                                                        float* __restrict__ Hout, int N) {
    using C = GatherCfg<DOUT>;
    constexpr int L = C::L, S = C::S, M = C::M;
    constexpr int NPW = C::NPW, NPB = C::NPB;
    const int wave = threadIdx.x >> 6, lane = threadIdx.x & 63;
    const int sub = lane / L, cl = lane % L;
    const uint2* __restrict__ P2 = (const uint2*)P;
    float4* __restrict__ H4 = (float4*)Hout;
    const int base = blockIdx.x * NPB + wave * NPW + sub;
    #pragma unroll 1
    for (int m = 0; m < M; ++m) {
        int n = base + m * S;
        if (n >= N) continue;
        int beg = rowptr[n], end = rowptr[n + 1];
        float4 a0 = {0, 0, 0, 0}, a1 = {0, 0, 0, 0}, a2 = {0, 0, 0, 0}, a3 = {0, 0, 0, 0};
        int j = beg;
        while (j < end && (j & 3)) { bfacc(a0, P2[(size_t)adj[j] * L + cl]); ++j; }
        for (; j + 8 <= end; j += 8) {
            int4 sA = *(const int4*)(adj + j);
            int4 sB = *(const int4*)(adj + j + 4);
            uint2 p0 = P2[(size_t)sA.x * L + cl];
            uint2 p1 = P2[(size_t)sA.y * L + cl];
            uint2 p2 = P2[(size_t)sA.z * L + cl];
            uint2 p3 = P2[(size_t)sA.w * L + cl];
            uint2 p4 = P2[(size_t)sB.x * L + cl];
            uint2 p5 = P2[(size_t)sB.y * L + cl];
            uint2 p6 = P2[(size_t)sB.z * L + cl];
            uint2 p7 = P2[(size_t)sB.w * L + cl];
            bfacc(a0, p0); bfacc(a1, p1); bfacc(a2, p2); bfacc(a3, p3);
            bfacc(a0, p4); bfacc(a1, p5); bfacc(a2, p6); bfacc(a3, p7);
        }
        if (j + 4 <= end) {
            int4 sA = *(const int4*)(adj + j);
            bfacc(a0, P2[(size_t)sA.x * L + cl]);
            bfacc(a1, P2[(size_t)sA.y * L + cl]);
            bfacc(a2, P2[(size_t)sA.z * L + cl]);
            bfacc(a3, P2[(size_t)sA.w * L + cl]);
            j += 4;
        }
        for (; j < end; ++j) bfacc(a0, P2[(size_t)adj[j] * L + cl]);
        int deg = end - beg;
        float inv = deg > 0 ? 1.0f / (float)deg : 0.0f;
        float4 r = H4[(size_t)n * L + cl];
        float4 o;
        o.x = fmaxf((a0.x + a1.x + a2.x + a3.x) * inv + r.x, 0.0f);
        o.y = fmaxf((a0.y + a1.y + a2.y + a3.y) * inv + r.y, 0.0f);
        o.z = fmaxf((a0.z + a1.z + a2.z + a3.z) * inv + r.z, 0.0f);
        o.w = fmaxf((a0.w + a1.w + a2.w + a3.w) * inv + r.w, 0.0f);
        H4[(size_t)n * L + cl] = o;
    }
}

__global__ __launch_bounds__(256) void k_head(const float* __restrict__ H3,
                                              const float* __restrict__ Wreg,
                                              const float* __restrict__ breg,
                                              const float* __restrict__ Wcls,
                                              const float* __restrict__ bcls,
                                              float* __restrict__ out, int N) {
    int i = blockIdx.x * 256 + threadIdx.x;
    if (i >= N) return;
    const float4* h = (const float4*)(H3 + (size_t)i * 16);
    float reg = 0.f, cls = 0.f;
    #pragma unroll
    for (int k4 = 0; k4 < 4; ++k4) {
        float4 hv = h[k4];
        float4 wr = ((const float4*)Wreg)[k4];
        float4 wc = ((const float4*)Wcls)[k4];
        reg += hv.x * wr.x + hv.y * wr.y + hv.z * wr.z + hv.w * wr.w;
        cls += hv.x * wc.x + hv.y * wc.y + hv.z * wc.z + hv.w * wc.w;
    }
    out[i] = reg + breg[0];
    out[(size_t)N + i] = cls + bcls[0];
}

extern "C" void kernel_launch(void* const* d_in, const int* in_sizes, int n_in,
                              void* d_out, int out_size, void* d_ws, size_t ws_size,
                              hipStream_t stream) {
    const float* x    = (const float*)d_in[0];
    const int*   ei   = (const int*)d_in[1];
    const float* W1l  = (const float*)d_in[2];
    const float* b1l  = (const float*)d_in[3];
    const float* W1r  = (const float*)d_in[4];
    const float* W2l  = (const float*)d_in[5];
    const float* b2l  = (const float*)d_in[6];
    const float* W2r  = (const float*)d_in[7];
    const float* W3l  = (const float*)d_in[8];
    const float* b3l  = (const float*)d_in[9];
    const float* W3r  = (const float*)d_in[10];
    const float* Wreg = (const float*)d_in[11];
    const float* breg = (const float*)d_in[12];
    const float* Wcls = (const float*)d_in[13];
    const float* bcls = (const float*)d_in[14];

    const int N = in_sizes[0] / 128;
    const int E = in_sizes[1] / 2;
    const int* src = ei;
    const int* dst = ei + E;

    char* ws = (char*)d_ws;
    size_t off = 0;
    auto alloc = [&](size_t bytes) -> void* {
        void* p = ws + off;
        off += (bytes + 255) & ~(size_t)255;
        return p;
    };
    int*   rowptr = (int*)alloc((size_t)(N + 1) * 4);
    int*   bcnt   = (int*)alloc(1024);
    int*   bcur   = (int*)alloc(1024);
    int*   boff   = (int*)alloc(1028);
    int*   adj    = (int*)alloc((size_t)E * 4);
    unsigned short* A = (unsigned short*)alloc((size_t)N * 64 * 2);  // bf16 P
    float* B      = (float*)alloc((size_t)N * 64 * 4);  // h1; doubles as T during CSR build
    float* C      = (float*)alloc((size_t)N * 32 * 4);  // h2
    float* D      = (float*)alloc((size_t)N * 16 * 4);  // h3
    int*   T      = (int*)B;                             // packed edges, E*4B <= N*64*4B

    const int NBK = (N + 1023) >> 10;     // buckets (196; must be <= 256)

    // ---- CSR build ----
    hipMemsetAsync(bcnt, 0, 1024, stream);
    k_bcount<<<1024, 256, 0, stream>>>(dst, E, N, bcnt);
    k_bscan<<<1, 256, 0, stream>>>(bcnt, boff, bcur, NBK, E);
    k_bucket<<<(E + BTILE - 1) / BTILE, 256, 0, stream>>>(src, dst, E, N, boff, bcur, T, NBK);
    k_csr<<<NBK, 1024, 0, stream>>>(T, boff, rowptr, adj, N, E);

    const int PB = 64;   // nodes per proj_mfma block (4 waves x 16)
    constexpr int G64 = GatherCfg<64>::NPB;
    constexpr int G32 = GatherCfg<32>::NPB;
    constexpr int G16 = GatherCfg<16>::NPB;

    // ---- layer 1: 128 -> 64 ----
    proj_mfma<128, 64><<<(N + PB - 1) / PB, 256, 0, stream>>>(x, W1l, W1r, b1l, A, B, N);
    gather_kernel<64><<<(N + G64 - 1) / G64, 256, 0, stream>>>(A, rowptr, adj, B, N);
    // ---- layer 2: 64 -> 32 ----
    proj_mfma<64, 32><<<(N + PB - 1) / PB, 256, 0, stream>>>(B, W2l, W2r, b2l, A, C, N);
    gather_kernel<32><<<(N + G32 - 1) / G32, 256, 0, stream>>>(A, rowptr, adj, C, N);
    // ---- layer 3: 32 -> 16 ----
    proj_mfma<32, 16><<<(N + PB - 1) / PB, 256, 0, stream>>>(C, W3l, W3r, b3l, A, D, N);
    gather_kernel<16><<<(N + G16 - 1) / G16, 256, 0, stream>>>(A, rowptr, adj, D, N);

    // ---- heads ----
    k_head<<<(N + 255) / 256, 256, 0, stream>>>(D, Wreg, breg, Wcls, bcls, (float*)d_out, N);
}